// Round 1
// baseline (1357.777 us; speedup 1.0000x reference)
//
#include <hip/hip_runtime.h>
#include <hip/hip_bf16.h>

// Linear attention (non-causal): per head
//   KV = sum_n k'[n] (x) v[n],  ksum = sum_n k'[n]
//   out[n] = (q'[n] @ KV) / (q'[n] . ksum)
// (reference's /128 on v and *128 at the end cancel exactly)
// Shapes: b=4, h=16 -> 64 heads, n=8192, d=128, all fp32.

#define BH 64
#define N 8192
#define D 128
#define CHUNKS 16
#define RPC (N / CHUNKS)   // 512 rows per chunk
#define SUB 32             // rows staged per iteration
#define HEAD_WS (D * D + D) // 16512 floats per head in ws
#define EPSF 1e-6f

__device__ __forceinline__ float fmap(float x) {
    // elu(x) + 1 + eps
    return x > 0.0f ? (x + (1.0f + EPSF)) : (__expf(x) + EPSF);
}

// ---------------- Phase 1: KV + ksum reduction ----------------
// grid (CHUNKS, BH), block 256. Thread (td = t>>4, te = t&15) owns
// d-cols {td*4..+3, 64+td*4..+3} and e-cols {te*4..+3, 64+te*4..+3}.
__global__ __launch_bounds__(256) void la_phase1(const float* __restrict__ kg,
                                                 const float* __restrict__ vg,
                                                 float* __restrict__ ws) {
    __shared__ float sk[SUB][D];
    __shared__ float sv[SUB][D];

    const int head  = blockIdx.y;
    const int chunk = blockIdx.x;
    const int t  = threadIdx.x;
    const int te = t & 15;
    const int td = t >> 4;
    const int c4 = t & 31;   // staging float4-column (constant across i)
    const int r0 = t >> 5;   // staging base row

    const float* kh = kg + (size_t)head * N * D;
    const float* vh = vg + (size_t)head * N * D;
    float* kvw = ws + (size_t)head * HEAD_WS;
    float* ksw = kvw + D * D;

    float4 acc[8][2];
#pragma unroll
    for (int a = 0; a < 8; ++a) {
        acc[a][0] = make_float4(0.f, 0.f, 0.f, 0.f);
        acc[a][1] = make_float4(0.f, 0.f, 0.f, 0.f);
    }
    float4 ks4 = make_float4(0.f, 0.f, 0.f, 0.f);

    for (int s = 0; s < RPC / SUB; ++s) {
        const int rowbase = chunk * RPC + s * SUB;
        __syncthreads();  // protect LDS reuse
#pragma unroll
        for (int i = 0; i < 4; ++i) {
            const int row = r0 + 8 * i;
            const size_t ga = (size_t)(rowbase + row) * D + c4 * 4;
            float4 kf = *(const float4*)(kh + ga);
            kf.x = fmap(kf.x); kf.y = fmap(kf.y); kf.z = fmap(kf.z); kf.w = fmap(kf.w);
            *(float4*)(&sk[row][c4 * 4]) = kf;
            ks4.x += kf.x; ks4.y += kf.y; ks4.z += kf.z; ks4.w += kf.w;
            *(float4*)(&sv[row][c4 * 4]) = *(const float4*)(vh + ga);
        }
        __syncthreads();
#pragma unroll 2
        for (int n = 0; n < SUB; ++n) {
            const float4 ka = *(const float4*)(&sk[n][td * 4]);
            const float4 kb = *(const float4*)(&sk[n][64 + td * 4]);
            const float4 va = *(const float4*)(&sv[n][te * 4]);
            const float4 vb = *(const float4*)(&sv[n][64 + te * 4]);
            const float kr[8] = {ka.x, ka.y, ka.z, ka.w, kb.x, kb.y, kb.z, kb.w};
#pragma unroll
            for (int a = 0; a < 8; ++a) {
                acc[a][0].x = fmaf(kr[a], va.x, acc[a][0].x);
                acc[a][0].y = fmaf(kr[a], va.y, acc[a][0].y);
                acc[a][0].z = fmaf(kr[a], va.z, acc[a][0].z);
                acc[a][0].w = fmaf(kr[a], va.w, acc[a][0].w);
                acc[a][1].x = fmaf(kr[a], vb.x, acc[a][1].x);
                acc[a][1].y = fmaf(kr[a], vb.y, acc[a][1].y);
                acc[a][1].z = fmaf(kr[a], vb.z, acc[a][1].z);
                acc[a][1].w = fmaf(kr[a], vb.w, acc[a][1].w);
            }
        }
    }

#pragma unroll
    for (int a = 0; a < 8; ++a) {
        const int da = (a < 4) ? (td * 4 + a) : (64 + td * 4 + (a - 4));
        float* dst = kvw + (size_t)da * D;
        atomicAdd(dst + te * 4 + 0, acc[a][0].x);
        atomicAdd(dst + te * 4 + 1, acc[a][0].y);
        atomicAdd(dst + te * 4 + 2, acc[a][0].z);
        atomicAdd(dst + te * 4 + 3, acc[a][0].w);
        atomicAdd(dst + 64 + te * 4 + 0, acc[a][1].x);
        atomicAdd(dst + 64 + te * 4 + 1, acc[a][1].y);
        atomicAdd(dst + 64 + te * 4 + 2, acc[a][1].z);
        atomicAdd(dst + 64 + te * 4 + 3, acc[a][1].w);
    }
    atomicAdd(ksw + c4 * 4 + 0, ks4.x);
    atomicAdd(ksw + c4 * 4 + 1, ks4.y);
    atomicAdd(ksw + c4 * 4 + 2, ks4.z);
    atomicAdd(ksw + c4 * 4 + 3, ks4.w);
}

// ---------------- Phase 2: out = (q'@KV) / (q'.ksum) ----------------
// grid (CHUNKS, BH), block 256. Thread (tr = t>>4, tc = t&15) owns rows
// {tr*2, tr*2+1} of the 32-row tile and cols {tc*4..+3, 64+tc*4..+3}.
// LDS: KV 64KB + q-tile 16KB = 80KB exactly -> 2 blocks/CU.
__global__ __launch_bounds__(256) void la_phase2(const float* __restrict__ qg,
                                                 const float* __restrict__ ws,
                                                 float* __restrict__ og) {
    __shared__ float skv[D * D];    // 64 KB, linear
    __shared__ float sq[SUB * D];   // 16 KB, XOR-swizzled rows

    const int head  = blockIdx.y;
    const int chunk = blockIdx.x;
    const int t  = threadIdx.x;
    const int tc = t & 15;
    const int tr = t >> 4;

    const float* qh = qg + (size_t)head * N * D;
    float* oh = og + (size_t)head * N * D;
    const float* kvw = ws + (size_t)head * HEAD_WS;
    const float* ksw = kvw + D * D;

    // load KV into LDS (16 float4 per thread), coalesced
#pragma unroll
    for (int i = 0; i < 16; ++i) {
        const int idx = (t + 256 * i) * 4;
        *(float4*)(&skv[idx]) = *(const float4*)(kvw + idx);
    }

    const int row0 = tr * 2;
    const int row1 = tr * 2 + 1;
    const int x0 = (row0 & 3) << 3;  // q-tile XOR swizzle per row
    const int x1 = (row1 & 3) << 3;

    for (int s = 0; s < RPC / SUB; ++s) {
        const int rowbase = chunk * RPC + s * SUB;
        __syncthreads();  // covers initial KV load + LDS reuse
#pragma unroll
        for (int i = 0; i < 4; ++i) {
            const int idx = t + 256 * i;
            const int row = idx >> 5;
            const int cc  = idx & 31;
            float4 qf = *(const float4*)(qh + (size_t)(rowbase + row) * D + cc * 4);
            qf.x = fmap(qf.x); qf.y = fmap(qf.y); qf.z = fmap(qf.z); qf.w = fmap(qf.w);
            const int col = (cc * 4) ^ ((row & 3) << 3);
            *(float4*)(&sq[row * D + col]) = qf;
        }
        __syncthreads();

        float4 a0A = make_float4(0.f, 0.f, 0.f, 0.f);
        float4 a0B = make_float4(0.f, 0.f, 0.f, 0.f);
        float4 a1A = make_float4(0.f, 0.f, 0.f, 0.f);
        float4 a1B = make_float4(0.f, 0.f, 0.f, 0.f);
        float n0 = 0.f, n1 = 0.f;
        const float* sq0 = sq + row0 * D;
        const float* sq1 = sq + row1 * D;

#pragma unroll 4
        for (int d = 0; d < D; ++d) {
            const float ksd = ksw[d];  // uniform -> scalar load, L1-resident
            const float4 kva = *(const float4*)(&skv[d * D + tc * 4]);
            const float4 kvb = *(const float4*)(&skv[d * D + 64 + tc * 4]);
            const float q0 = sq0[d ^ x0];
            const float q1 = sq1[d ^ x1];
            n0 = fmaf(q0, ksd, n0);
            n1 = fmaf(q1, ksd, n1);
            a0A.x = fmaf(q0, kva.x, a0A.x);
            a0A.y = fmaf(q0, kva.y, a0A.y);
            a0A.z = fmaf(q0, kva.z, a0A.z);
            a0A.w = fmaf(q0, kva.w, a0A.w);
            a0B.x = fmaf(q0, kvb.x, a0B.x);
            a0B.y = fmaf(q0, kvb.y, a0B.y);
            a0B.z = fmaf(q0, kvb.z, a0B.z);
            a0B.w = fmaf(q0, kvb.w, a0B.w);
            a1A.x = fmaf(q1, kva.x, a1A.x);
            a1A.y = fmaf(q1, kva.y, a1A.y);
            a1A.z = fmaf(q1, kva.z, a1A.z);
            a1A.w = fmaf(q1, kva.w, a1A.w);
            a1B.x = fmaf(q1, kvb.x, a1B.x);
            a1B.y = fmaf(q1, kvb.y, a1B.y);
            a1B.z = fmaf(q1, kvb.z, a1B.z);
            a1B.w = fmaf(q1, kvb.w, a1B.w);
        }

        const float inv0 = 1.0f / n0;
        const float inv1 = 1.0f / n1;
        float* o0 = oh + (size_t)(rowbase + row0) * D;
        float* o1 = oh + (size_t)(rowbase + row1) * D;
        float4 w;
        w.x = a0A.x * inv0; w.y = a0A.y * inv0; w.z = a0A.z * inv0; w.w = a0A.w * inv0;
        *(float4*)(o0 + tc * 4) = w;
        w.x = a0B.x * inv0; w.y = a0B.y * inv0; w.z = a0B.z * inv0; w.w = a0B.w * inv0;
        *(float4*)(o0 + 64 + tc * 4) = w;
        w.x = a1A.x * inv1; w.y = a1A.y * inv1; w.z = a1A.z * inv1; w.w = a1A.w * inv1;
        *(float4*)(o1 + tc * 4) = w;
        w.x = a1B.x * inv1; w.y = a1B.y * inv1; w.z = a1B.z * inv1; w.w = a1B.w * inv1;
        *(float4*)(o1 + 64 + tc * 4) = w;
    }
}

extern "C" void kernel_launch(void* const* d_in, const int* in_sizes, int n_in,
                              void* d_out, int out_size, void* d_ws, size_t ws_size,
                              hipStream_t stream) {
    const float* q = (const float*)d_in[0];
    const float* k = (const float*)d_in[1];
    const float* v = (const float*)d_in[2];
    float* out = (float*)d_out;
    float* ws  = (float*)d_ws;

    // zero the KV/ksum accumulators (ws is poisoned 0xAA before every launch)
    hipMemsetAsync(d_ws, 0, (size_t)BH * HEAD_WS * sizeof(float), stream);

    dim3 grid(CHUNKS, BH);
    dim3 block(256);
    la_phase1<<<grid, block, 0, stream>>>(k, v, ws);
    la_phase2<<<grid, block, 0, stream>>>(q, ws, out);
}